// Round 2
// baseline (1534.937 us; speedup 1.0000x reference)
//
#include <hip/hip_runtime.h>
#include <hip/hip_bf16.h>
#include <math.h>

#define NDIM 300
#define KP   304
#define NCOLS 1800

typedef __hip_bfloat16 bf16;

// ---------------- tiny constant-folding kernels ----------------
__global__ void small_pre(
    const float* __restrict__ Wn, const float* __restrict__ bn,
    const float* __restrict__ Wxy, const float* __restrict__ bxy,
    const float* __restrict__ Wloc, const float* __restrict__ bloc,
    const float* __restrict__ bobj,
    const float* __restrict__ Wfus,
    const float* __restrict__ vocab,
    float* __restrict__ Wn1, float* __restrict__ Wn2,
    float* __restrict__ Mxy, float* __restrict__ bgeo,
    float* __restrict__ vf5, float* __restrict__ t0, float* __restrict__ t1)
{
    int i = blockIdx.x * blockDim.x + threadIdx.x;
    if (i < 900) {                       // Wn1 = Wn @ Wloc[300:600]
        int r = i / 300, c = i % 300;
        float s = 0.f;
        for (int k = 0; k < 300; k++) s += Wn[r*300+k] * Wloc[(300+k)*300+c];
        Wn1[i] = s;
    } else if (i < 1800) {               // Wn2 = Wn @ Wloc[600:900]
        int j = i - 900; int r = j/300, c = j%300;
        float s = 0.f;
        for (int k = 0; k < 300; k++) s += Wn[r*300+k] * Wloc[(600+k)*300+c];
        Wn2[j] = s;
    } else if (i < 2400) {               // Mxy = Wxy @ Wloc[0:300]
        int j = i - 1800; int r = j/300, c = j%300;
        float s = 0.f;
        for (int k = 0; k < 300; k++) s += Wxy[r*300+k] * Wloc[k*300+c];
        Mxy[j] = s;
    } else if (i < 2700) {               // bgeo = bloc + bobj + bxy@Wloc0 + bn@(Wloc1+Wloc2)
        int c = i - 2400;
        float s = bloc[c] + bobj[c];
        for (int k = 0; k < 300; k++) s += bxy[k] * Wloc[k*300+c];
        for (int k = 0; k < 300; k++) s += bn[k] * (Wloc[(300+k)*300+c] + Wloc[(600+k)*300+c]);
        bgeo[c] = s;
    } else if (i < 4200) {               // vf5 = vocab[2:7] @ Wfus[300:600]
        int j = i - 2700; int p = j/300, c = j%300;
        float s = 0.f;
        for (int k = 0; k < 300; k++) s += vocab[(2+p)*300+k] * Wfus[(300+k)*300+c];
        vf5[j] = s;
    } else if (i < 4500) {               // t0 = vocab[0] @ Wfus[0:300]
        int c = i - 4200;
        float s = 0.f;
        for (int k = 0; k < 300; k++) s += vocab[k] * Wfus[k*300+c];
        t0[c] = s;
    } else if (i < 4800) {               // t1 = vocab[1] @ Wfus[0:300]
        int c = i - 4500;
        float s = 0.f;
        for (int k = 0; k < 300; k++) s += vocab[300+k] * Wfus[k*300+c];
        t1[c] = s;
    }
}

__global__ void small_pre2(
    const float* __restrict__ We, const float* __restrict__ bfus,
    const float* __restrict__ vf5, const float* __restrict__ t0, const float* __restrict__ t1,
    float* __restrict__ E8)
{
    int i = blockIdx.x * blockDim.x + threadIdx.x;
    if (i >= 2400) return;
    int r = i / 300, c = i % 300;
    const float* src;
    if (r == 0) src = t0;
    else if (r == 1) src = t1;
    else if (r == 7) src = bfus;
    else src = vf5 + (r - 2) * 300;
    float s = 0.f;
    for (int k = 0; k < 300; k++) s += src[k] * We[k*300+c];
    E8[i] = s;
}

// pack the 6 weight matrices into Wcat[304][1800] (+ bias vector)
__global__ void pack_w(
    const float* __restrict__ Wq, const float* __restrict__ Wk,
    const float* __restrict__ Wv, const float* __restrict__ Wskip,
    const float* __restrict__ Wobj,
    const float* __restrict__ Wn1, const float* __restrict__ Wn2,
    const float* __restrict__ bq, const float* __restrict__ bk,
    const float* __restrict__ bv, const float* __restrict__ bskip,
    float* __restrict__ Wcat, float* __restrict__ bcat)
{
    int i = blockIdx.x * blockDim.x + threadIdx.x;
    if (i < NCOLS) {
        int seg = i / 300, jj = i % 300;
        float b = 0.f;
        if (seg == 0) b = bq[jj]; else if (seg == 1) b = bk[jj];
        else if (seg == 2) b = bv[jj]; else if (seg == 3) b = bskip[jj];
        bcat[i] = b;
    }
    if (i < KP * NCOLS) {
        int k = i / NCOLS, j = i % NCOLS;
        int seg = j / 300, jj = j % 300;
        float v = 0.f;
        if (k < 300) {
            switch (seg) {
                case 0: v = Wq[k*300+jj]; break;
                case 1: v = Wk[k*300+jj]; break;
                case 2: v = Wv[k*300+jj]; break;
                case 3: v = Wskip[k*300+jj]; break;
                case 4: v = Wobj[k*300+jj] - Wobj[(300+k)*300+jj]; break;
                default: v = Wobj[(300+k)*300+jj]; break;
            }
        } else if (k < 303) {
            if (seg == 4) v = Wn1[(k-300)*300+jj];
            else if (seg == 5) v = Wn2[(k-300)*300+jj];
        }
        Wcat[i] = v;
    }
}

// ---------------- fused per-node GEMM: [N,304] @ [304,1800] ----------------
// 128x128 tile, BK=8, 256 threads, 8x8 per-thread microtile.
// Epilogue routes cols to Q/K/V(bf16), skip(fp32 -> d_out), Pi/Pj(bf16).
__global__ __launch_bounds__(256) void gemm_k1(
    const float* __restrict__ X, const float* __restrict__ Nrm,
    const float* __restrict__ W, const float* __restrict__ bcat,
    bf16* __restrict__ Q, bf16* __restrict__ Kf, bf16* __restrict__ V,
    float* __restrict__ Ot, bf16* __restrict__ Pi, bf16* __restrict__ Pj,
    int Nrows)
{
    __shared__ float As[8][128];   // [k][m]
    __shared__ float Ws[8][128];   // [k][n]
    const int tid  = threadIdx.x;
    const int row0 = blockIdx.y * 128;
    const int col0 = blockIdx.x * 128;
    const int tm = (tid >> 4) * 8;
    const int tn = (tid & 15) * 8;

    float acc[8][8];
    #pragma unroll
    for (int i = 0; i < 8; i++)
        #pragma unroll
        for (int j = 0; j < 8; j++) acc[i][j] = 0.f;

    const int ar = tid >> 1;            // 0..127
    const int ak = (tid & 1) * 4;       // 0 or 4
    const int arow = min(row0 + ar, Nrows - 1);
    const int wk = tid >> 5;            // 0..7
    const int wn = (tid & 31) * 4;      // 0..124

    for (int k0 = 0; k0 < KP; k0 += 8) {
        int g = k0 + ak;
        if (g + 3 < 300) {
            const float4 v = *(const float4*)(X + (size_t)arow * 300 + g);
            As[ak  ][ar] = v.x; As[ak+1][ar] = v.y;
            As[ak+2][ar] = v.z; As[ak+3][ar] = v.w;
        } else {
            #pragma unroll
            for (int t = 0; t < 4; t++) {
                int gg = g + t;
                float v = 0.f;
                if (gg < 300)      v = X[(size_t)arow * 300 + gg];
                else if (gg < 303) v = Nrm[(size_t)arow * 3 + (gg - 300)];
                As[ak + t][ar] = v;
            }
        }
        {
            int col = col0 + wn;
            float4 v = make_float4(0.f, 0.f, 0.f, 0.f);
            if (col < NCOLS) v = *(const float4*)(W + (size_t)(k0 + wk) * NCOLS + col);
            Ws[wk][wn  ] = v.x; Ws[wk][wn+1] = v.y;
            Ws[wk][wn+2] = v.z; Ws[wk][wn+3] = v.w;
        }
        __syncthreads();
        #pragma unroll
        for (int kk = 0; kk < 8; kk++) {
            const float4 a0 = *(const float4*)&As[kk][tm];
            const float4 a1 = *(const float4*)&As[kk][tm + 4];
            const float4 b0 = *(const float4*)&Ws[kk][tn];
            const float4 b1 = *(const float4*)&Ws[kk][tn + 4];
            float a[8] = {a0.x, a0.y, a0.z, a0.w, a1.x, a1.y, a1.z, a1.w};
            float b[8] = {b0.x, b0.y, b0.z, b0.w, b1.x, b1.y, b1.z, b1.w};
            #pragma unroll
            for (int i = 0; i < 8; i++)
                #pragma unroll
                for (int j = 0; j < 8; j++)
                    acc[i][j] = fmaf(a[i], b[j], acc[i][j]);
        }
        __syncthreads();
    }
    #pragma unroll
    for (int i = 0; i < 8; i++) {
        int row = row0 + tm + i;
        if (row >= Nrows) break;
        #pragma unroll
        for (int j = 0; j < 8; j++) {
            int col = col0 + tn + j;
            if (col >= NCOLS) continue;
            float v = acc[i][j] + bcat[col];
            int seg = col / 300, jj = col - seg * 300;
            size_t idx = (size_t)row * 300 + jj;
            switch (seg) {
                case 0: Q [idx] = __float2bfloat16(v); break;
                case 1: Kf[idx] = __float2bfloat16(v); break;
                case 2: V [idx] = __float2bfloat16(v); break;
                case 3: Ot[idx] = v;                   break;
                case 4: Pi[idx] = __float2bfloat16(v); break;
                default: Pj[idx] = __float2bfloat16(v); break;
            }
        }
    }
}

// ---------------- per-edge phase 1: tanh/softmax/alpha ----------------
__global__ __launch_bounds__(256) void edge_phase1(
    const int* __restrict__ ei, const float* __restrict__ ea,
    const bf16* __restrict__ Q, const bf16* __restrict__ Kf,
    const bf16* __restrict__ Pi, const bf16* __restrict__ Pj,
    const float* __restrict__ Mxy, const float* __restrict__ bgeo,
    const float* __restrict__ E8,
    const float* __restrict__ Wcls, const float* __restrict__ bcls,
    float* __restrict__ coef, float* __restrict__ aexp, float* __restrict__ den,
    int E)
{
    const int wid  = threadIdx.x >> 6;
    const int lane = threadIdx.x & 63;
    const int e = blockIdx.x * 4 + wid;
    if (e >= E) return;
    const int s = ei[e];
    const int d = ei[E + e];
    const float ea0 = ea[(size_t)e*4+0], ea1 = ea[(size_t)e*4+1];
    const float ea2 = ea[(size_t)e*4+2], ea3 = ea[(size_t)e*4+3];
    const size_t drow = (size_t)d * 300, srow = (size_t)s * 300;

    float tt[5];
    #pragma unroll
    for (int r = 0; r < 5; r++) {
        int c = lane + 64 * r;
        float v = 0.f;
        if (c < 300) {
            v = __bfloat162float(Pi[drow + c]) + __bfloat162float(Pj[srow + c])
              + ea2 * Mxy[c] + ea3 * Mxy[300 + c] + bgeo[c];
            v = fminf(fmaxf(v, -15.f), 15.f);
            float ex = __expf(2.f * v);
            v = (ex - 1.f) / (ex + 1.f);          // tanh
        }
        tt[r] = v;
    }
    float lg[5];
    #pragma unroll
    for (int cl = 0; cl < 5; cl++) {
        float p = 0.f;
        #pragma unroll
        for (int r = 0; r < 5; r++) {
            int c = lane + 64 * r;
            if (c < 300) p += tt[r] * Wcls[c * 5 + cl];
        }
        #pragma unroll
        for (int m = 1; m < 64; m <<= 1) p += __shfl_xor(p, m, 64);
        lg[cl] = p + bcls[cl];
    }
    float mx = lg[0];
    #pragma unroll
    for (int cl = 1; cl < 5; cl++) mx = fmaxf(mx, lg[cl]);
    float pr[5], psum = 0.f;
    #pragma unroll
    for (int cl = 0; cl < 5; cl++) { pr[cl] = __expf(lg[cl] - mx); psum += pr[cl]; }
    const float pinv = 1.f / psum;
    #pragma unroll
    for (int cl = 0; cl < 5; cl++) pr[cl] *= pinv;

    const float ctop = ea0 > 0.f ? 1.f : 0.f;
    const float cbot = ea1 < 0.f ? 1.f : 0.f;
    if (lane < 8) {
        float cv;
        switch (lane) {
            case 0: cv = ctop;  break; case 1: cv = cbot;  break;
            case 2: cv = pr[0]; break; case 3: cv = pr[1]; break;
            case 4: cv = pr[2]; break; case 5: cv = pr[3]; break;
            case 6: cv = pr[4]; break; default: cv = 1.f;  break;
        }
        coef[(size_t)e * 8 + lane] = cv;
    }
    // alpha = q . (k + ef) per head
    float h0 = 0.f, h1 = 0.f, h2 = 0.f, h3 = 0.f;
    #pragma unroll
    for (int r = 0; r < 5; r++) {
        int c = lane + 64 * r;
        if (c < 300) {
            float efv = ctop * E8[c] + cbot * E8[300 + c]
                      + pr[0] * E8[600 + c] + pr[1] * E8[900 + c] + pr[2] * E8[1200 + c]
                      + pr[3] * E8[1500 + c] + pr[4] * E8[1800 + c] + E8[2100 + c];
            float p = __bfloat162float(Q[drow + c])
                    * (__bfloat162float(Kf[srow + c]) + efv);
            if (r == 0) h0 += p;
            else if (r == 1) { if (c < 75)  h0 += p; else h1 += p; }
            else if (r == 2) { if (c < 150) h1 += p; else h2 += p; }
            else if (r == 3) { if (c < 225) h2 += p; else h3 += p; }
            else h3 += p;
        }
    }
    #pragma unroll
    for (int m = 1; m < 64; m <<= 1) {
        h0 += __shfl_xor(h0, m, 64);
        h1 += __shfl_xor(h1, m, 64);
        h2 += __shfl_xor(h2, m, 64);
        h3 += __shfl_xor(h3, m, 64);
    }
    const float isc = 0.11547005383792516f;   // 1/sqrt(75)
    if (lane < 4) {
        float av = (lane == 0) ? h0 : (lane == 1) ? h1 : (lane == 2) ? h2 : h3;
        av = __expf(av * isc);                 // segment_max skipped: exp can't overflow at this scale
        aexp[(size_t)e * 4 + lane] = av;
        atomicAdd(&den[(size_t)d * 4 + lane], av);
    }
}

// ---------------- per-edge phase 2: weighted scatter ----------------
__global__ __launch_bounds__(256) void edge_phase2(
    const int* __restrict__ ei,
    const bf16* __restrict__ Vf, const float* __restrict__ E8,
    const float* __restrict__ coef, const float* __restrict__ aexp,
    const float* __restrict__ den,
    float* __restrict__ Ot, int E)
{
    const int wid  = threadIdx.x >> 6;
    const int lane = threadIdx.x & 63;
    const int e = blockIdx.x * 4 + wid;
    if (e >= E) return;
    const int s = ei[e];
    const int d = ei[E + e];
    const float c0 = coef[(size_t)e*8+0], c1 = coef[(size_t)e*8+1];
    const float c2 = coef[(size_t)e*8+2], c3 = coef[(size_t)e*8+3];
    const float c4 = coef[(size_t)e*8+4], c5 = coef[(size_t)e*8+5];
    const float c6 = coef[(size_t)e*8+6];
    const float w0 = aexp[(size_t)e*4+0] / den[(size_t)d*4+0];
    const float w1 = aexp[(size_t)e*4+1] / den[(size_t)d*4+1];
    const float w2 = aexp[(size_t)e*4+2] / den[(size_t)d*4+2];
    const float w3 = aexp[(size_t)e*4+3] / den[(size_t)d*4+3];
    const size_t drow = (size_t)d * 300, srow = (size_t)s * 300;
    #pragma unroll
    for (int r = 0; r < 5; r++) {
        int c = lane + 64 * r;
        if (c < 300) {
            float efv = c0 * E8[c] + c1 * E8[300 + c] + c2 * E8[600 + c] + c3 * E8[900 + c]
                      + c4 * E8[1200 + c] + c5 * E8[1500 + c] + c6 * E8[1800 + c] + E8[2100 + c];
            float w = (r == 0) ? w0
                    : (r == 1) ? (c < 75  ? w0 : w1)
                    : (r == 2) ? (c < 150 ? w1 : w2)
                    : (r == 3) ? (c < 225 ? w2 : w3)
                    : w3;
            atomicAdd(&Ot[drow + c], (__bfloat162float(Vf[srow + c]) + efv) * w);
        }
    }
}

// ---------------- launch ----------------
extern "C" void kernel_launch(void* const* d_in, const int* in_sizes, int n_in,
                              void* d_out, int out_size, void* d_ws, size_t ws_size,
                              hipStream_t stream)
{
    const float* x     = (const float*)d_in[0];
    const int*   ei    = (const int*)  d_in[1];
    const float* ea    = (const float*)d_in[2];
    const float* on    = (const float*)d_in[3];
    const float* Wq    = (const float*)d_in[4];
    const float* bq    = (const float*)d_in[5];
    const float* Wk    = (const float*)d_in[6];
    const float* bk    = (const float*)d_in[7];
    const float* Wv    = (const float*)d_in[8];
    const float* bv    = (const float*)d_in[9];
    const float* We    = (const float*)d_in[10];
    const float* Wn    = (const float*)d_in[11];
    const float* bn    = (const float*)d_in[12];
    const float* Wxy   = (const float*)d_in[13];
    const float* bxy   = (const float*)d_in[14];
    const float* Wloc  = (const float*)d_in[15];
    const float* bloc  = (const float*)d_in[16];
    const float* Wobj  = (const float*)d_in[17];
    const float* bobj  = (const float*)d_in[18];
    const float* Wfus  = (const float*)d_in[19];
    const float* bfus  = (const float*)d_in[20];
    const float* Wcls  = (const float*)d_in[21];
    const float* bcls  = (const float*)d_in[22];
    const float* Wskip = (const float*)d_in[23];
    const float* bskip = (const float*)d_in[24];
    const float* vocab = (const float*)d_in[25];

    const int N = in_sizes[0] / NDIM;
    const int E = in_sizes[1] / 2;

    // ---- workspace layout: bf16 region first, then fp32 region ----
    const size_t nodeElems = (size_t)N * 300;
    size_t need = 0;
    need += 5 * nodeElems * sizeof(bf16);                       // Q,K,V,Pi,Pj
    size_t f32Elems = (size_t)KP * NCOLS + NCOLS               // Wcat, bcat
                    + (size_t)E * 8 + (size_t)E * 4            // coef, aexp
                    + (size_t)N * 4                            // den
                    + 904 + 904 + 600 + 304 + 1504 + 304 + 304 + 2400;
    need += f32Elems * sizeof(float);
    if (ws_size < need) return;   // clean failure signal instead of OOB fault

    bf16* wsh = (bf16*)d_ws;
    bf16* Qb  = wsh;                 bf16* Kb  = Qb + nodeElems;
    bf16* Vb  = Kb + nodeElems;      bf16* Pib = Vb + nodeElems;
    bf16* Pjb = Pib + nodeElems;
    float* ws = (float*)(Pjb + nodeElems);
    size_t o = 0;
    float* Wcat  = ws + o; o += (size_t)KP * NCOLS;
    float* bcat  = ws + o; o += NCOLS;
    float* coefb = ws + o; o += (size_t)E * 8;
    float* aexpb = ws + o; o += (size_t)E * 4;
    float* denb  = ws + o; o += (size_t)N * 4;
    float* Wn1   = ws + o; o += 904;
    float* Wn2   = ws + o; o += 904;
    float* Mxyb  = ws + o; o += 600;
    float* bgeo  = ws + o; o += 304;
    float* vf5   = ws + o; o += 1504;
    float* t0b   = ws + o; o += 304;
    float* t1b   = ws + o; o += 304;
    float* E8b   = ws + o; o += 2400;
    (void)n_in; (void)out_size;

    hipMemsetAsync(denb, 0, (size_t)N * 4 * sizeof(float), stream);
    small_pre<<<19, 256, 0, stream>>>(Wn, bn, Wxy, bxy, Wloc, bloc, bobj, Wfus, vocab,
                                      Wn1, Wn2, Mxyb, bgeo, vf5, t0b, t1b);
    small_pre2<<<10, 256, 0, stream>>>(We, bfus, vf5, t0b, t1b, E8b);
    pack_w<<<(KP * NCOLS + 255) / 256, 256, 0, stream>>>(
        Wq, Wk, Wv, Wskip, Wobj, Wn1, Wn2, bq, bk, bv, bskip, Wcat, bcat);

    dim3 g1((NCOLS + 127) / 128, (N + 127) / 128);
    gemm_k1<<<g1, 256, 0, stream>>>(x, on, Wcat, bcat,
                                    Qb, Kb, Vb, (float*)d_out, Pib, Pjb, N);

    const int eb = (E + 3) / 4;
    edge_phase1<<<eb, 256, 0, stream>>>(ei, ea, Qb, Kb, Pib, Pjb, Mxyb, bgeo, E8b,
                                        Wcls, bcls, coefb, aexpb, denb, E);
    edge_phase2<<<eb, 256, 0, stream>>>(ei, Vb, E8b, coefb, aexpb, denb,
                                        (float*)d_out, E);
}

// Round 3
// 1179.238 us; speedup vs baseline: 1.3016x; 1.3016x over previous
//
#include <hip/hip_runtime.h>
#include <hip/hip_bf16.h>
#include <math.h>

#define NDIM 300
#define KPAD 320          // K padded: 300 x-dims + 3 normal dims + zeros
#define NREAL 1800
#define NPAD 1920         // 15 tiles of 128

typedef __hip_bfloat16 bf16;
typedef __attribute__((ext_vector_type(8))) short short8;   // 8 bf16 (4 VGPRs)
typedef __attribute__((ext_vector_type(4))) float f32x4;

__device__ __forceinline__ void gl_lds16(const void* g, void* l) {
    __builtin_amdgcn_global_load_lds(
        (const __attribute__((address_space(1))) void*)g,
        (__attribute__((address_space(3))) void*)l, 16, 0, 0);
}

// ---------------- tiny constant-folding kernels ----------------
__global__ void small_pre(
    const float* __restrict__ Wn, const float* __restrict__ bn,
    const float* __restrict__ Wxy, const float* __restrict__ bxy,
    const float* __restrict__ Wloc, const float* __restrict__ bloc,
    const float* __restrict__ bobj,
    const float* __restrict__ Wfus,
    const float* __restrict__ vocab,
    float* __restrict__ Wn1, float* __restrict__ Wn2,
    float* __restrict__ Mxy, float* __restrict__ bgeo,
    float* __restrict__ vf5, float* __restrict__ t0, float* __restrict__ t1)
{
    int i = blockIdx.x * blockDim.x + threadIdx.x;
    if (i < 900) {                       // Wn1 = Wn @ Wloc[300:600]
        int r = i / 300, c = i % 300;
        float s = 0.f;
        for (int k = 0; k < 300; k++) s += Wn[r*300+k] * Wloc[(300+k)*300+c];
        Wn1[i] = s;
    } else if (i < 1800) {               // Wn2 = Wn @ Wloc[600:900]
        int j = i - 900; int r = j/300, c = j%300;
        float s = 0.f;
        for (int k = 0; k < 300; k++) s += Wn[r*300+k] * Wloc[(600+k)*300+c];
        Wn2[j] = s;
    } else if (i < 2400) {               // Mxy = Wxy @ Wloc[0:300]
        int j = i - 1800; int r = j/300, c = j%300;
        float s = 0.f;
        for (int k = 0; k < 300; k++) s += Wxy[r*300+k] * Wloc[k*300+c];
        Mxy[j] = s;
    } else if (i < 2700) {               // bgeo = bloc + bobj + bxy@Wloc0 + bn@(Wloc1+Wloc2)
        int c = i - 2400;
        float s = bloc[c] + bobj[c];
        for (int k = 0; k < 300; k++) s += bxy[k] * Wloc[k*300+c];
        for (int k = 0; k < 300; k++) s += bn[k] * (Wloc[(300+k)*300+c] + Wloc[(600+k)*300+c]);
        bgeo[c] = s;
    } else if (i < 4200) {               // vf5 = vocab[2:7] @ Wfus[300:600]
        int j = i - 2700; int p = j/300, c = j%300;
        float s = 0.f;
        for (int k = 0; k < 300; k++) s += vocab[(2+p)*300+k] * Wfus[(300+k)*300+c];
        vf5[j] = s;
    } else if (i < 4500) {               // t0 = vocab[0] @ Wfus[0:300]
        int c = i - 4200;
        float s = 0.f;
        for (int k = 0; k < 300; k++) s += vocab[k] * Wfus[k*300+c];
        t0[c] = s;
    } else if (i < 4800) {               // t1 = vocab[1] @ Wfus[0:300]
        int c = i - 4500;
        float s = 0.f;
        for (int k = 0; k < 300; k++) s += vocab[300+k] * Wfus[k*300+c];
        t1[c] = s;
    }
}

__global__ void small_pre2(
    const float* __restrict__ We, const float* __restrict__ bfus,
    const float* __restrict__ vf5, const float* __restrict__ t0, const float* __restrict__ t1,
    float* __restrict__ E8)
{
    int i = blockIdx.x * blockDim.x + threadIdx.x;
    if (i >= 2400) return;
    int r = i / 300, c = i % 300;
    const float* src;
    if (r == 0) src = t0;
    else if (r == 1) src = t1;
    else if (r == 7) src = bfus;
    else src = vf5 + (r - 2) * 300;
    float s = 0.f;
    for (int k = 0; k < 300; k++) s += src[k] * We[k*300+c];
    E8[i] = s;
}

// pack weights into WcatT[NPAD][KPAD] bf16 (transposed, K contiguous) + bcat fp32
__global__ void pack_w(
    const float* __restrict__ Wq, const float* __restrict__ Wk,
    const float* __restrict__ Wv, const float* __restrict__ Wskip,
    const float* __restrict__ Wobj,
    const float* __restrict__ Wn1, const float* __restrict__ Wn2,
    const float* __restrict__ bq, const float* __restrict__ bk,
    const float* __restrict__ bv, const float* __restrict__ bskip,
    bf16* __restrict__ WcatT, float* __restrict__ bcat)
{
    int i = blockIdx.x * blockDim.x + threadIdx.x;
    if (i < NREAL) {
        int seg = i / 300, jj = i % 300;
        float b = 0.f;
        if (seg == 0) b = bq[jj]; else if (seg == 1) b = bk[jj];
        else if (seg == 2) b = bv[jj]; else if (seg == 3) b = bskip[jj];
        bcat[i] = b;
    }
    if (i < NPAD * KPAD) {
        int c = i / KPAD, k = i % KPAD;   // c = output col, k = input dim
        float v = 0.f;
        if (c < NREAL) {
            int seg = c / 300, jj = c % 300;
            if (k < 300) {
                switch (seg) {
                    case 0: v = Wq[k*300+jj]; break;
                    case 1: v = Wk[k*300+jj]; break;
                    case 2: v = Wv[k*300+jj]; break;
                    case 3: v = Wskip[k*300+jj]; break;
                    case 4: v = Wobj[k*300+jj] - Wobj[(300+k)*300+jj]; break;
                    default: v = Wobj[(300+k)*300+jj]; break;
                }
            } else if (k < 303) {
                if (seg == 4) v = Wn1[(k-300)*300+jj];
                else if (seg == 5) v = Wn2[(k-300)*300+jj];
            }
        }
        WcatT[i] = __float2bfloat16(v);
    }
}

// ---------------- MFMA node-GEMM: [N,320]bf16 @ [320,1920]bf16 ----------------
// 128x128 tile, BK=32, 4 waves each computing 4x4 grid of 16x16x32 MFMA tiles.
// A converted fp32->bf16 on the fly (ds_write staging); B via global_load_lds.
__global__ __launch_bounds__(256) void gemm_mfma(
    const float* __restrict__ X, const float* __restrict__ Nrm,
    const bf16* __restrict__ Bt, const float* __restrict__ bcat,
    bf16* __restrict__ Q, bf16* __restrict__ Kf, bf16* __restrict__ V,
    float* __restrict__ Ot, bf16* __restrict__ Pi, bf16* __restrict__ Pj,
    int M)
{
    __shared__ __align__(16) bf16 As[128 * 32];   // [row][k] k-contiguous
    __shared__ __align__(16) bf16 Bs[128 * 32];   // [col][k] k-contiguous

    const int tid  = threadIdx.x;
    const int wave = tid >> 6;
    const int lane = tid & 63;
    const int r0 = blockIdx.y * 128;
    const int c0 = blockIdx.x * 128;
    const int wm = (wave >> 1) * 64;
    const int wn = (wave & 1) * 64;
    const int lr = lane & 15;
    const int lq = lane >> 4;

    f32x4 acc[4][4];
    #pragma unroll
    for (int i = 0; i < 4; i++)
        #pragma unroll
        for (int j = 0; j < 4; j++) acc[i][j] = (f32x4){0.f, 0.f, 0.f, 0.f};

    // A staging: thread t -> row t>>1, k-halfrow (t&1)*16
    const int arow_l = tid >> 1;
    const int akp    = (tid & 1) * 16;
    const int agrow  = min(r0 + arow_l, M - 1);
    const float* xr = X + (size_t)agrow * 300;
    const float* nr = Nrm + (size_t)agrow * 3;
    // B staging: wave w covers cols w*32 + h*16 + lane/4, k-part (lane&3)*8
    const int bcol_l = lane >> 2;
    const int bkp    = (lane & 3) * 8;

    for (int kb = 0; kb < KPAD; kb += 32) {
        // ---- stage A (fp32 -> bf16 via registers) ----
        {
            int g = kb + akp;
            union { bf16 h[16]; short8 s[2]; } u;
            if (g + 16 <= 300) {
                const float4 f0 = *(const float4*)(xr + g);
                const float4 f1 = *(const float4*)(xr + g + 4);
                const float4 f2 = *(const float4*)(xr + g + 8);
                const float4 f3 = *(const float4*)(xr + g + 12);
                u.h[0]=__float2bfloat16(f0.x); u.h[1]=__float2bfloat16(f0.y);
                u.h[2]=__float2bfloat16(f0.z); u.h[3]=__float2bfloat16(f0.w);
                u.h[4]=__float2bfloat16(f1.x); u.h[5]=__float2bfloat16(f1.y);
                u.h[6]=__float2bfloat16(f1.z); u.h[7]=__float2bfloat16(f1.w);
                u.h[8]=__float2bfloat16(f2.x); u.h[9]=__float2bfloat16(f2.y);
                u.h[10]=__float2bfloat16(f2.z); u.h[11]=__float2bfloat16(f2.w);
                u.h[12]=__float2bfloat16(f3.x); u.h[13]=__float2bfloat16(f3.y);
                u.h[14]=__float2bfloat16(f3.z); u.h[15]=__float2bfloat16(f3.w);
            } else {
                #pragma unroll
                for (int t = 0; t < 16; t++) {
                    int gg = g + t;
                    float v = 0.f;
                    if (gg < 300)      v = xr[gg];
                    else if (gg < 303) v = nr[gg - 300];
                    u.h[t] = __float2bfloat16(v);
                }
            }
            *(short8*)&As[arow_l * 32 + akp]     = u.s[0];
            *(short8*)&As[arow_l * 32 + akp + 8] = u.s[1];
        }
        // ---- stage B (async 16B direct-to-LDS) ----
        #pragma unroll
        for (int h = 0; h < 2; h++) {
            int cloc = wave * 32 + h * 16;
            const bf16* g = Bt + (size_t)(c0 + cloc + bcol_l) * KPAD + kb + bkp;
            gl_lds16(g, &Bs[cloc * 32]);
        }
        __syncthreads();
        // ---- compute ----
        short8 af[4], bfr[4];
        #pragma unroll
        for (int i = 0; i < 4; i++)
            af[i] = *(const short8*)&As[(wm + i * 16 + lr) * 32 + lq * 8];
        #pragma unroll
        for (int j = 0; j < 4; j++)
            bfr[j] = *(const short8*)&Bs[(wn + j * 16 + lr) * 32 + lq * 8];
        #pragma unroll
        for (int i = 0; i < 4; i++)
            #pragma unroll
            for (int j = 0; j < 4; j++)
                acc[i][j] = __builtin_amdgcn_mfma_f32_16x16x32_bf16(
                    af[i], bfr[j], acc[i][j], 0, 0, 0);
        __syncthreads();
    }

    // ---- epilogue: C/D layout col=lane&15, row=(lane>>4)*4+reg ----
    #pragma unroll
    for (int j = 0; j < 4; j++) {
        int col = c0 + wn + j * 16 + lr;
        if (col >= NREAL) continue;
        int seg = col / 300, jj = col - seg * 300;
        float b = bcat[col];
        #pragma unroll
        for (int i = 0; i < 4; i++) {
            #pragma unroll
            for (int rg = 0; rg < 4; rg++) {
                int row = r0 + wm + i * 16 + lq * 4 + rg;
                if (row >= M) continue;
                float v = acc[i][j][rg] + b;
                size_t idx = (size_t)row * 300 + jj;
                switch (seg) {
                    case 0: Q [idx] = __float2bfloat16(v); break;
                    case 1: Kf[idx] = __float2bfloat16(v); break;
                    case 2: V [idx] = __float2bfloat16(v); break;
                    case 3: Ot[idx] = v;                   break;
                    case 4: Pi[idx] = __float2bfloat16(v); break;
                    default: Pj[idx] = __float2bfloat16(v); break;
                }
            }
        }
    }
}

// ---------------- per-edge phase 1: tanh/softmax/alpha ----------------
__global__ __launch_bounds__(256) void edge_phase1(
    const int* __restrict__ ei, const float* __restrict__ ea,
    const bf16* __restrict__ Q, const bf16* __restrict__ Kf,
    const bf16* __restrict__ Pi, const bf16* __restrict__ Pj,
    const float* __restrict__ Mxy, const float* __restrict__ bgeo,
    const float* __restrict__ E8,
    const float* __restrict__ Wcls, const float* __restrict__ bcls,
    float* __restrict__ coef, float* __restrict__ aexp, float* __restrict__ den,
    int E)
{
    const int wid  = threadIdx.x >> 6;
    const int lane = threadIdx.x & 63;
    const int e = blockIdx.x * 4 + wid;
    if (e >= E) return;
    const int s = ei[e];
    const int d = ei[E + e];
    const float ea0 = ea[(size_t)e*4+0], ea1 = ea[(size_t)e*4+1];
    const float ea2 = ea[(size_t)e*4+2], ea3 = ea[(size_t)e*4+3];
    const size_t drow = (size_t)d * 300, srow = (size_t)s * 300;

    float tt[5];
    #pragma unroll
    for (int r = 0; r < 5; r++) {
        int c = lane + 64 * r;
        float v = 0.f;
        if (c < 300) {
            v = __bfloat162float(Pi[drow + c]) + __bfloat162float(Pj[srow + c])
              + ea2 * Mxy[c] + ea3 * Mxy[300 + c] + bgeo[c];
            v = fminf(fmaxf(v, -15.f), 15.f);
            float ex = __expf(2.f * v);
            v = (ex - 1.f) / (ex + 1.f);          // tanh
        }
        tt[r] = v;
    }
    float lg[5];
    #pragma unroll
    for (int cl = 0; cl < 5; cl++) {
        float p = 0.f;
        #pragma unroll
        for (int r = 0; r < 5; r++) {
            int c = lane + 64 * r;
            if (c < 300) p += tt[r] * Wcls[c * 5 + cl];
        }
        #pragma unroll
        for (int m = 1; m < 64; m <<= 1) p += __shfl_xor(p, m, 64);
        lg[cl] = p + bcls[cl];
    }
    float mx = lg[0];
    #pragma unroll
    for (int cl = 1; cl < 5; cl++) mx = fmaxf(mx, lg[cl]);
    float pr[5], psum = 0.f;
    #pragma unroll
    for (int cl = 0; cl < 5; cl++) { pr[cl] = __expf(lg[cl] - mx); psum += pr[cl]; }
    const float pinv = 1.f / psum;
    #pragma unroll
    for (int cl = 0; cl < 5; cl++) pr[cl] *= pinv;

    const float ctop = ea0 > 0.f ? 1.f : 0.f;
    const float cbot = ea1 < 0.f ? 1.f : 0.f;
    if (lane < 8) {
        float cv;
        switch (lane) {
            case 0: cv = ctop;  break; case 1: cv = cbot;  break;
            case 2: cv = pr[0]; break; case 3: cv = pr[1]; break;
            case 4: cv = pr[2]; break; case 5: cv = pr[3]; break;
            case 6: cv = pr[4]; break; default: cv = 1.f;  break;
        }
        coef[(size_t)e * 8 + lane] = cv;
    }
    // alpha = q . (k + ef) per head
    float h0 = 0.f, h1 = 0.f, h2 = 0.f, h3 = 0.f;
    #pragma unroll
    for (int r = 0; r < 5; r++) {
        int c = lane + 64 * r;
        if (c < 300) {
            float efv = ctop * E8[c] + cbot * E8[300 + c]
                      + pr[0] * E8[600 + c] + pr[1] * E8[900 + c] + pr[2] * E8[1200 + c]
                      + pr[3] * E8[1500 + c] + pr[4] * E8[1800 + c] + E8[2100 + c];
            float p = __bfloat162float(Q[drow + c])
                    * (__bfloat162float(Kf[srow + c]) + efv);
            if (r == 0) h0 += p;
            else if (r == 1) { if (c < 75)  h0 += p; else h1 += p; }
            else if (r == 2) { if (c < 150) h1 += p; else h2 += p; }
            else if (r == 3) { if (c < 225) h2 += p; else h3 += p; }
            else h3 += p;
        }
    }
    #pragma unroll
    for (int m = 1; m < 64; m <<= 1) {
        h0 += __shfl_xor(h0, m, 64);
        h1 += __shfl_xor(h1, m, 64);
        h2 += __shfl_xor(h2, m, 64);
        h3 += __shfl_xor(h3, m, 64);
    }
    const float isc = 0.11547005383792516f;   // 1/sqrt(75)
    if (lane < 4) {
        float av = (lane == 0) ? h0 : (lane == 1) ? h1 : (lane == 2) ? h2 : h3;
        av = __expf(av * isc);                 // segment_max skipped: exp can't overflow at this scale
        aexp[(size_t)e * 4 + lane] = av;
        atomicAdd(&den[(size_t)d * 4 + lane], av);
    }
}

// ---------------- per-edge phase 2: weighted scatter ----------------
__global__ __launch_bounds__(256) void edge_phase2(
    const int* __restrict__ ei,
    const bf16* __restrict__ Vf, const float* __restrict__ E8,
    const float* __restrict__ coef, const float* __restrict__ aexp,
    const float* __restrict__ den,
    float* __restrict__ Ot, int E)
{
    const int wid  = threadIdx.x >> 6;
    const int lane = threadIdx.x & 63;
    const int e = blockIdx.x * 4 + wid;
    if (e >= E) return;
    const int s = ei[e];
    const int d = ei[E + e];
    const float c0 = coef[(size_t)e*8+0], c1 = coef[(size_t)e*8+1];
    const float c2 = coef[(size_t)e*8+2], c3 = coef[(size_t)e*8+3];
    const float c4 = coef[(size_t)e*8+4], c5 = coef[(size_t)e*8+5];
    const float c6 = coef[(size_t)e*8+6];
    const float w0 = aexp[(size_t)e*4+0] / den[(size_t)d*4+0];
    const float w1 = aexp[(size_t)e*4+1] / den[(size_t)d*4+1];
    const float w2 = aexp[(size_t)e*4+2] / den[(size_t)d*4+2];
    const float w3 = aexp[(size_t)e*4+3] / den[(size_t)d*4+3];
    const size_t drow = (size_t)d * 300, srow = (size_t)s * 300;
    #pragma unroll
    for (int r = 0; r < 5; r++) {
        int c = lane + 64 * r;
        if (c < 300) {
            float efv = c0 * E8[c] + c1 * E8[300 + c] + c2 * E8[600 + c] + c3 * E8[900 + c]
                      + c4 * E8[1200 + c] + c5 * E8[1500 + c] + c6 * E8[1800 + c] + E8[2100 + c];
            float w = (r == 0) ? w0
                    : (r == 1) ? (c < 75  ? w0 : w1)
                    : (r == 2) ? (c < 150 ? w1 : w2)
                    : (r == 3) ? (c < 225 ? w2 : w3)
                    : w3;
            atomicAdd(&Ot[drow + c], (__bfloat162float(Vf[srow + c]) + efv) * w);
        }
    }
}

// ---------------- launch ----------------
extern "C" void kernel_launch(void* const* d_in, const int* in_sizes, int n_in,
                              void* d_out, int out_size, void* d_ws, size_t ws_size,
                              hipStream_t stream)
{
    const float* x     = (const float*)d_in[0];
    const int*   ei    = (const int*)  d_in[1];
    const float* ea    = (const float*)d_in[2];
    const float* on    = (const float*)d_in[3];
    const float* Wq    = (const float*)d_in[4];
    const float* bq    = (const float*)d_in[5];
    const float* Wk    = (const float*)d_in[6];
    const float* bk    = (const float*)d_in[7];
    const float* Wv    = (const float*)d_in[8];
    const float* bv    = (const float*)d_in[9];
    const float* We    = (const float*)d_in[10];
    const float* Wn    = (const float*)d_in[11];
    const float* bn    = (const float*)d_in[12];
    const float* Wxy   = (const float*)d_in[13];
    const float* bxy   = (const float*)d_in[14];
    const float* Wloc  = (const float*)d_in[15];
    const float* bloc  = (const float*)d_in[16];
    const float* Wobj  = (const float*)d_in[17];
    const float* bobj  = (const float*)d_in[18];
    const float* Wfus  = (const float*)d_in[19];
    const float* bfus  = (const float*)d_in[20];
    const float* Wcls  = (const float*)d_in[21];
    const float* bcls  = (const float*)d_in[22];
    const float* Wskip = (const float*)d_in[23];
    const float* bskip = (const float*)d_in[24];
    const float* vocab = (const float*)d_in[25];

    const int N = in_sizes[0] / NDIM;
    const int E = in_sizes[1] / 2;

    // ---- workspace layout: bf16 region first, then fp32 region ----
    const size_t nodeElems = (size_t)N * 300;
    const size_t wcatElems = (size_t)NPAD * KPAD;
    size_t need = (5 * nodeElems + wcatElems) * sizeof(bf16);
    size_t f32Elems = NREAL                                     // bcat
                    + (size_t)E * 8 + (size_t)E * 4             // coef, aexp
                    + (size_t)N * 4                             // den
                    + 904 + 904 + 600 + 304 + 1504 + 304 + 304 + 2400;
    need += f32Elems * sizeof(float);
    if (ws_size < need) return;   // clean failure signal instead of OOB fault

    bf16* wsh = (bf16*)d_ws;
    bf16* Qb    = wsh;                 bf16* Kb  = Qb + nodeElems;
    bf16* Vb    = Kb + nodeElems;      bf16* Pib = Vb + nodeElems;
    bf16* Pjb   = Pib + nodeElems;
    bf16* WcatT = Pjb + nodeElems;
    float* ws = (float*)(WcatT + wcatElems);
    size_t o = 0;
    float* bcat  = ws + o; o += NREAL;
    float* coefb = ws + o; o += (size_t)E * 8;
    float* aexpb = ws + o; o += (size_t)E * 4;
    float* denb  = ws + o; o += (size_t)N * 4;
    float* Wn1   = ws + o; o += 904;
    float* Wn2   = ws + o; o += 904;
    float* Mxyb  = ws + o; o += 600;
    float* bgeo  = ws + o; o += 304;
    float* vf5   = ws + o; o += 1504;
    float* t0b   = ws + o; o += 304;
    float* t1b   = ws + o; o += 304;
    float* E8b   = ws + o; o += 2400;
    (void)n_in; (void)out_size;

    hipMemsetAsync(denb, 0, (size_t)N * 4 * sizeof(float), stream);
    small_pre<<<19, 256, 0, stream>>>(Wn, bn, Wxy, bxy, Wloc, bloc, bobj, Wfus, vocab,
                                      Wn1, Wn2, Mxyb, bgeo, vf5, t0b, t1b);
    small_pre2<<<10, 256, 0, stream>>>(We, bfus, vf5, t0b, t1b, E8b);
    pack_w<<<(NPAD * KPAD + 255) / 256, 256, 0, stream>>>(
        Wq, Wk, Wv, Wskip, Wobj, Wn1, Wn2, bq, bk, bv, bskip, WcatT, bcat);

    dim3 g1(NPAD / 128, (N + 127) / 128);
    gemm_mfma<<<g1, 256, 0, stream>>>(x, on, WcatT, bcat,
                                      Qb, Kb, Vb, (float*)d_out, Pib, Pjb, N);

    const int eb = (E + 3) / 4;
    edge_phase1<<<eb, 256, 0, stream>>>(ei, ea, Qb, Kb, Pib, Pjb, Mxyb, bgeo, E8b,
                                        Wcls, bcls, coefb, aexpb, denb, E);
    edge_phase2<<<eb, 256, 0, stream>>>(ei, Vb, E8b, coefb, aexpb, denb,
                                        (float*)d_out, E);
}